// Round 21
// baseline (180.423 us; speedup 1.0000x reference)
//
#include <hip/hip_runtime.h>
#include <hip/hip_bf16.h>

#define B_ 2
#define T_ 2048
#define C_ 1024
#define H_ 16
#define DH_ 64

typedef __attribute__((ext_vector_type(8))) short bf16x8;
typedef __attribute__((ext_vector_type(4))) float f32x4;
typedef __attribute__((ext_vector_type(4))) unsigned int u32x4;

#define DEVI static __device__ __forceinline__

DEVI unsigned short f2bf(float f) {
  unsigned int u = __float_as_uint(f);
  u = (u + 0x7fffu + ((u >> 16) & 1u)) >> 16;
  return (unsigned short)u;
}

DEVI f32x4 mfma16(bf16x8 a, bf16x8 b, f32x4 c) {
  return __builtin_amdgcn_mfma_f32_16x16x32_bf16(a, b, c, 0, 0, 0);
}

DEVI void gload_lds16(const unsigned short* g, unsigned short* l) {
  __builtin_amdgcn_global_load_lds(
      (const __attribute__((address_space(1))) unsigned int*)g,
      (__attribute__((address_space(3))) unsigned int*)l, 16, 0, 0);
}

DEVI unsigned int cvtpk_bf16(float lo, float hi) {
  unsigned int r;
  asm("v_cvt_pk_bf16_f32 %0, %1, %2" : "=v"(r) : "v"(lo), "v"(hi));
  return r;
}

// inverse of the R3 K-row permutation (HW-verified in R19)
DEVI int kperm_inv(int R) {
  return (R & 3) | (((R >> 4) & 1) << 2) | (((R >> 2) & 1) << 3) |
         (((R >> 5) & 1) << 4) | (((R >> 3) & 1) << 5);
}

// ---- fused pre-pass: x cast + w_qkv transpose-cast + w_proj transpose-cast ----
__global__ __launch_bounds__(256) void prep_kernel(
    const float* __restrict__ x, const float* __restrict__ w_qkv,
    const float* __restrict__ w_proj, unsigned short* __restrict__ xb,
    unsigned short* __restrict__ wqkvT, unsigned short* __restrict__ wprojT) {
  __shared__ float tile[32][33];
  int b = blockIdx.x, tid = threadIdx.x;
  if (b < 4096) {
    int i = b * 256 + tid;
    float4 v = reinterpret_cast<const float4*>(x)[i];
    ushort4 o;
    o.x = f2bf(v.x); o.y = f2bf(v.y); o.z = f2bf(v.z); o.w = f2bf(v.w);
    reinterpret_cast<ushort4*>(xb)[i] = o;
  } else {
    const float* in;
    unsigned short* out;
    int R, C, bb;
    if (b < 7168) { bb = b - 4096; in = w_qkv; out = wqkvT; R = 1024; C = 3072; }
    else          { bb = b - 7168; in = w_proj; out = wprojT; R = 1024; C = 1024; }
    int nbx = C >> 5;
    int c0 = (bb % nbx) * 32, r0 = (bb / nbx) * 32;
    int tx = tid & 31, ty = tid >> 5;
#pragma unroll
    for (int j = 0; j < 32; j += 8)
      tile[ty + j][tx] = in[(size_t)(r0 + ty + j) * C + c0 + tx];
    __syncthreads();
#pragma unroll
    for (int j = 0; j < 32; j += 8)
      out[(size_t)(c0 + ty + j) * R + r0 + tx] = f2bf(tile[tx][ty + j]);
  }
}

// ---- QKV GEMM: 128x192 tile, BK=64, 4 waves, 8-phase, 2 blocks/CU (R18) ----
__global__ __launch_bounds__(256, 2) void gemm192_qkv(
    const unsigned short* __restrict__ A, const unsigned short* __restrict__ Bt,
    const float* __restrict__ bias,
    unsigned short* __restrict__ qbuf, unsigned short* __restrict__ kbuf,
    unsigned short* __restrict__ vtbuf) {
  __shared__ __attribute__((aligned(16))) unsigned short As[2][128 * 64];
  __shared__ __attribute__((aligned(16))) unsigned short Bs[2][192 * 64];
  const int Kd = 1024;
  int tid = threadIdx.x;
  int lane = tid & 63, w = tid >> 6;
  int wn = w;
  int lrow = lane & 15, lgrp = lane >> 4;

  int g = blockIdx.x;
  int gs = (g & 7) * 64 + (g >> 3);
  int by = gs >> 4, bx = gs & 15;
  int bm = by * 128, bn = bx * 192;
  const unsigned short* Ab = A + (size_t)bm * Kd;
  const unsigned short* Bb = Bt + (size_t)bn * Kd;

  int sL[2], scl[2];
#pragma unroll
  for (int it = 0; it < 2; ++it) {
    int c = tid + it * 256;
    int L = c >> 3, s = c & 7, v = s ^ (L & 7);
    sL[it] = L;
    scl[it] = (v >> 2) * 32 + (v & 3) * 8;
  }

  auto stgA = [&](int t, int h) {
    unsigned short* dst = As[t & 1] + h * 4096;
    int k0 = t << 6;
#pragma unroll
    for (int it = 0; it < 2; ++it)
      gload_lds16(Ab + (size_t)(h * 64 + sL[it]) * Kd + k0 + scl[it],
                  dst + (tid + it * 256) * 8);
  };
  auto stgB3 = [&](int t, int th) {
    unsigned short* dst = Bs[t & 1] + th * 4096;
    int k0 = t << 6;
#pragma unroll
    for (int it = 0; it < 2; ++it)
      gload_lds16(Bb + (size_t)(th * 64 + sL[it]) * Kd + k0 + scl[it],
                  dst + (tid + it * 256) * 8);
  };

  auto lda = [&](const unsigned short* buf, int mi, int kk) -> bf16x8 {
    int row = mi * 16 + lrow;
    int s = ((kk << 2) | lgrp) ^ (row & 7);
    return *reinterpret_cast<const bf16x8*>((const char*)buf + row * 128 + s * 16);
  };
  auto ldb = [&](const unsigned short* buf, int ni, int kk) -> bf16x8 {
    int row = wn * 48 + ni * 16 + lrow;
    int s = ((kk << 2) | lgrp) ^ (row & 7);
    return *reinterpret_cast<const bf16x8*>((const char*)buf + row * 128 + s * 16);
  };

  f32x4 acc[8][3] = {};
  bf16x8 bfr[3][2], af[2][2];

#define PHASE_TAIL                                          \
  __builtin_amdgcn_s_barrier();                             \
  __builtin_amdgcn_s_setprio(1);

#define MFMA_TRI(base)                                      \
  _Pragma("unroll") for (int ii = 0; ii < 2; ++ii)          \
  _Pragma("unroll") for (int ni = 0; ni < 3; ++ni) {        \
    acc[(base) + ii][ni] = mfma16(af[ii][0], bfr[ni][0], acc[(base) + ii][ni]); \
    acc[(base) + ii][ni] = mfma16(af[ii][1], bfr[ni][1], acc[(base) + ii][ni]); \
  }

#define PHASE_END                                           \
  __builtin_amdgcn_s_setprio(0);                            \
  __builtin_amdgcn_s_barrier();

  stgA(0, 0); stgA(0, 1);
  stgB3(0, 0); stgB3(0, 1); stgB3(0, 2);
  stgB3(1, 0); stgB3(1, 1); stgB3(1, 2);
  asm volatile("s_waitcnt vmcnt(6)" ::: "memory");
  __builtin_amdgcn_s_barrier();

#pragma unroll 1
  for (int j = 0; j < 8; ++j) {
    const bool nl = (j < 7);
    const int t1 = 2 * j + 1, t2 = 2 * j + 2, t3 = 2 * j + 3;

#pragma unroll
    for (int ni = 0; ni < 3; ++ni) { bfr[ni][0] = ldb(Bs[0], ni, 0); bfr[ni][1] = ldb(Bs[0], ni, 1); }
    af[0][0] = lda(As[0], 0, 0); af[0][1] = lda(As[0], 0, 1);
    af[1][0] = lda(As[0], 1, 0); af[1][1] = lda(As[0], 1, 1);
    stgA(t1, 0);
    PHASE_TAIL; MFMA_TRI(0); PHASE_END;

    af[0][0] = lda(As[0], 2, 0); af[0][1] = lda(As[0], 2, 1);
    af[1][0] = lda(As[0], 3, 0); af[1][1] = lda(As[0], 3, 1);
    stgA(t1, 1);
    if (nl) stgB3(t2, 0);
    PHASE_TAIL; MFMA_TRI(2); PHASE_END;

    af[0][0] = lda(As[0], 4, 0); af[0][1] = lda(As[0], 4, 1);
    af[1][0] = lda(As[0], 5, 0); af[1][1] = lda(As[0], 5, 1);
    if (nl) stgB3(t2, 1);
    PHASE_TAIL; MFMA_TRI(4); PHASE_END;

    af[0][0] = lda(As[0], 6, 0); af[0][1] = lda(As[0], 6, 1);
    af[1][0] = lda(As[0], 7, 0); af[1][1] = lda(As[0], 7, 1);
    if (nl) stgB3(t2, 2);
    PHASE_TAIL; MFMA_TRI(6);
    __builtin_amdgcn_s_setprio(0);
    if (nl) { asm volatile("s_waitcnt vmcnt(6)" ::: "memory"); }
    else    { asm volatile("s_waitcnt vmcnt(0)" ::: "memory"); }
    __builtin_amdgcn_s_barrier();

#pragma unroll
    for (int ni = 0; ni < 3; ++ni) { bfr[ni][0] = ldb(Bs[1], ni, 0); bfr[ni][1] = ldb(Bs[1], ni, 1); }
    af[0][0] = lda(As[1], 0, 0); af[0][1] = lda(As[1], 0, 1);
    af[1][0] = lda(As[1], 1, 0); af[1][1] = lda(As[1], 1, 1);
    if (nl) stgA(t2, 0);
    PHASE_TAIL; MFMA_TRI(0); PHASE_END;

    af[0][0] = lda(As[1], 2, 0); af[0][1] = lda(As[1], 2, 1);
    af[1][0] = lda(As[1], 3, 0); af[1][1] = lda(As[1], 3, 1);
    if (nl) { stgA(t2, 1); stgB3(t3, 0); }
    PHASE_TAIL; MFMA_TRI(2); PHASE_END;

    af[0][0] = lda(As[1], 4, 0); af[0][1] = lda(As[1], 4, 1);
    af[1][0] = lda(As[1], 5, 0); af[1][1] = lda(As[1], 5, 1);
    if (nl) stgB3(t3, 1);
    PHASE_TAIL; MFMA_TRI(4); PHASE_END;

    af[0][0] = lda(As[1], 6, 0); af[0][1] = lda(As[1], 6, 1);
    af[1][0] = lda(As[1], 7, 0); af[1][1] = lda(As[1], 7, 1);
    if (nl) stgB3(t3, 2);
    PHASE_TAIL; MFMA_TRI(6);
    __builtin_amdgcn_s_setprio(0);
    if (nl) { asm volatile("s_waitcnt vmcnt(6)" ::: "memory"); }
    __builtin_amdgcn_s_barrier();
  }
#undef PHASE_TAIL
#undef MFMA_TRI
#undef PHASE_END

  int c0 = bn + wn * 48;
#pragma unroll
  for (int ni = 0; ni < 3; ++ni) {
    int col = c0 + ni * 16 + lrow;
    float bv = bias[col];
    int which = col >> 10, cc = col & 1023;
    int h = cc >> 6, d = cc & 63;
#pragma unroll
    for (int mi = 0; mi < 8; ++mi) {
      int rowb = bm + mi * 16 + lgrp * 4;
      int b = rowb >> 11, tt = rowb & 2047;
      if (which == 2) {
        ushort4 pk;
        pk.x = f2bf(acc[mi][ni][0] + bv);
        pk.y = f2bf(acc[mi][ni][1] + bv);
        pk.z = f2bf(acc[mi][ni][2] + bv);
        pk.w = f2bf(acc[mi][ni][3] + bv);
        *reinterpret_cast<ushort4*>(vtbuf + ((size_t)((b * 16 + h) * 64 + d)) * T_ + tt) = pk;
      } else {
        unsigned short* dst = (which == 0) ? qbuf : kbuf;
        size_t base = ((size_t)(b * 16 + h) * T_ + tt) * DH_ + d;
#pragma unroll
        for (int r = 0; r < 4; ++r)
          dst[base + (size_t)r * DH_] = f2bf(acc[mi][ni][r] + bv);
      }
    }
  }
}

// ---- proj GEMM: 128x128 tile, BK=64, 4 waves, 8-phase, 2 blocks/CU (R18) ----
__global__ __launch_bounds__(256, 2) void gemm_proj(
    const unsigned short* __restrict__ A, const unsigned short* __restrict__ Bt,
    const float* __restrict__ bias, float* __restrict__ outp) {
  __shared__ __attribute__((aligned(16))) unsigned short As[2][128 * 64];
  __shared__ __attribute__((aligned(16))) unsigned short Bs[2][128 * 64];
  const int Kd = 1024, Nd = 1024;
  int tid = threadIdx.x;
  int lane = tid & 63, w = tid >> 6;
  int wn = w;
  int lrow = lane & 15, lgrp = lane >> 4;

  int g = blockIdx.x;
  int gs = (g & 7) * 32 + (g >> 3);
  int by = gs >> 3, bx = gs & 7;
  int bm = by * 128, bn = bx * 128;
  const unsigned short* Ab = A + (size_t)bm * Kd;
  const unsigned short* Bb = Bt + (size_t)bn * Kd;

  int sL[2], scl[2];
#pragma unroll
  for (int it = 0; it < 2; ++it) {
    int c = tid + it * 256;
    int L = c >> 3, s = c & 7, v = s ^ (L & 7);
    sL[it] = L;
    scl[it] = (v >> 2) * 32 + (v & 3) * 8;
  }

  auto stgA = [&](int t, int h) {
    unsigned short* dst = As[t & 1] + h * 4096;
    int k0 = t << 6;
#pragma unroll
    for (int it = 0; it < 2; ++it)
      gload_lds16(Ab + (size_t)(h * 64 + sL[it]) * Kd + k0 + scl[it],
                  dst + (tid + it * 256) * 8);
  };
  auto stgB = [&](int t, int h) {
    unsigned short* dst = Bs[t & 1] + h * 4096;
    int k0 = t << 6;
#pragma unroll
    for (int it = 0; it < 2; ++it)
      gload_lds16(Bb + (size_t)(h * 64 + sL[it]) * Kd + k0 + scl[it],
                  dst + (tid + it * 256) * 8);
  };

  auto lda = [&](const unsigned short* buf, int mi, int kk) -> bf16x8 {
    int row = mi * 16 + lrow;
    int s = ((kk << 2) | lgrp) ^ (row & 7);
    return *reinterpret_cast<const bf16x8*>((const char*)buf + row * 128 + s * 16);
  };
  auto ldb = [&](const unsigned short* buf, int ni, int kk) -> bf16x8 {
    int row = wn * 32 + ni * 16 + lrow;
    int s = ((kk << 2) | lgrp) ^ (row & 7);
    return *reinterpret_cast<const bf16x8*>((const char*)buf + row * 128 + s * 16);
  };

  f32x4 acc[8][2] = {};
  bf16x8 bfr[2][2], af[2][2];

#define PHASE_TAIL                                          \
  __builtin_amdgcn_s_barrier();                             \
  __builtin_amdgcn_s_setprio(1);

#define MFMA_DUO(base)                                      \
  _Pragma("unroll") for (int ii = 0; ii < 2; ++ii)          \
  _Pragma("unroll") for (int ni = 0; ni < 2; ++ni) {        \
    acc[(base) + ii][ni] = mfma16(af[ii][0], bfr[ni][0], acc[(base) + ii][ni]); \
    acc[(base) + ii][ni] = mfma16(af[ii][1], bfr[ni][1], acc[(base) + ii][ni]); \
  }

#define PHASE_END                                           \
  __builtin_amdgcn_s_setprio(0);                            \
  __builtin_amdgcn_s_barrier();

  stgA(0, 0); stgA(0, 1); stgB(0, 0); stgB(0, 1);
  stgB(1, 0); stgB(1, 1);
  asm volatile("s_waitcnt vmcnt(4)" ::: "memory");
  __builtin_amdgcn_s_barrier();

#pragma unroll 1
  for (int j = 0; j < 8; ++j) {
    const bool nl = (j < 7);
    const int t1 = 2 * j + 1, t2 = 2 * j + 2, t3 = 2 * j + 3;

#pragma unroll
    for (int ni = 0; ni < 2; ++ni) { bfr[ni][0] = ldb(Bs[0], ni, 0); bfr[ni][1] = ldb(Bs[0], ni, 1); }
    af[0][0] = lda(As[0], 0, 0); af[0][1] = lda(As[0], 0, 1);
    af[1][0] = lda(As[0], 1, 0); af[1][1] = lda(As[0], 1, 1);
    stgA(t1, 0);
    PHASE_TAIL; MFMA_DUO(0); PHASE_END;

    af[0][0] = lda(As[0], 2, 0); af[0][1] = lda(As[0], 2, 1);
    af[1][0] = lda(As[0], 3, 0); af[1][1] = lda(As[0], 3, 1);
    stgA(t1, 1);
    if (nl) stgB(t2, 0);
    PHASE_TAIL; MFMA_DUO(2); PHASE_END;

    af[0][0] = lda(As[0], 4, 0); af[0][1] = lda(As[0], 4, 1);
    af[1][0] = lda(As[0], 5, 0); af[1][1] = lda(As[0], 5, 1);
    if (nl) stgB(t2, 1);
    PHASE_TAIL; MFMA_DUO(4); PHASE_END;

    af[0][0] = lda(As[0], 6, 0); af[0][1] = lda(As[0], 6, 1);
    af[1][0] = lda(As[0], 7, 0); af[1][1] = lda(As[0], 7, 1);
    PHASE_TAIL; MFMA_DUO(6);
    __builtin_amdgcn_s_setprio(0);
    if (nl) { asm volatile("s_waitcnt vmcnt(4)" ::: "memory"); }
    else    { asm volatile("s_waitcnt vmcnt(0)" ::: "memory"); }
    __builtin_amdgcn_s_barrier();

#pragma unroll
    for (int ni = 0; ni < 2; ++ni) { bfr[ni][0] = ldb(Bs[1], ni, 0); bfr[ni][1] = ldb(Bs[1], ni, 1); }
    af[0][0] = lda(As[1], 0, 0); af[0][1] = lda(As[1], 0, 1);
    af[1][0] = lda(As[1], 1, 0); af[1][1] = lda(As[1], 1, 1);
    if (nl) stgA(t2, 0);
    PHASE_TAIL; MFMA_DUO(0); PHASE_END;

    af[0][0] = lda(As[1], 2, 0); af[0][1] = lda(As[1], 2, 1);
    af[1][0] = lda(As[1], 3, 0); af[1][1] = lda(As[1], 3, 1);
    if (nl) { stgA(t2, 1); stgB(t3, 0); }
    PHASE_TAIL; MFMA_DUO(2); PHASE_END;

    af[0][0] = lda(As[1], 4, 0); af[0][1] = lda(As[1], 4, 1);
    af[1][0] = lda(As[1], 5, 0); af[1][1] = lda(As[1], 5, 1);
    if (nl) stgB(t3, 1);
    PHASE_TAIL; MFMA_DUO(4); PHASE_END;

    af[0][0] = lda(As[1], 6, 0); af[0][1] = lda(As[1], 6, 1);
    af[1][0] = lda(As[1], 7, 0); af[1][1] = lda(As[1], 7, 1);
    PHASE_TAIL; MFMA_DUO(6);
    __builtin_amdgcn_s_setprio(0);
    if (nl) { asm volatile("s_waitcnt vmcnt(4)" ::: "memory"); }
    __builtin_amdgcn_s_barrier();
  }
#undef PHASE_TAIL
#undef MFMA_DUO
#undef PHASE_END

  int c0 = bn + wn * 32;
#pragma unroll
  for (int ni = 0; ni < 2; ++ni) {
    int col = c0 + ni * 16 + lrow;
    float bv = bias[col];
#pragma unroll
    for (int mi = 0; mi < 8; ++mi) {
      int rowb = bm + mi * 16 + lgrp * 4;
#pragma unroll
      for (int r = 0; r < 4; ++r)
        outp[(size_t)(rowb + r) * Nd + col] = acc[mi][ni][r] + bv;
    }
  }
}

// ---- flash attention: NO-MAX softmax, BARRIER-FREE (K/V direct from L2) ----
// K+V per head = 512KB; bh-locality keeps 4 heads (2MB) in each XCD's L2.
// No LDS, no __syncthreads: each wave runs fully async; fragment addresses
// absorb the K-row permutation (kperm_inv, verified in R19).
__global__ __launch_bounds__(256, 4) void attn_kernel(
    const unsigned short* __restrict__ qbuf,
    const unsigned short* __restrict__ kbuf,
    const unsigned short* __restrict__ vtbuf,
    unsigned short* __restrict__ attno) {
  int tid = threadIdx.x;
  int lane = tid & 63, w = tid >> 6;
  int lrow = lane & 15, lgrp = lane >> 4;

  int g = blockIdx.x;
  int s = g >> 8;
  int p = (g >> 3) & 7;
  int bh = (g & 7) | (((g >> 6) & 3) << 3);
  int qb = (s == 0) ? p : (s == 1) ? (31 - p) : (s == 2) ? (8 + p) : (23 - p);
  int wq0 = qb * 64 + w * 16;
  int nkb = qb + 1;

  const unsigned short* Qb = qbuf + (size_t)bh * T_ * DH_;
  const unsigned short* Kb = kbuf + (size_t)bh * T_ * DH_;
  const unsigned short* Vb = vtbuf + (size_t)bh * DH_ * T_;

  // per-lane fragment source addresses (permuted K rows; natural V^T rows)
  const unsigned short* kfp[4];
  const unsigned short* vfp[4];
#pragma unroll
  for (int ni = 0; ni < 4; ++ni) {
    kfp[ni] = Kb + (size_t)kperm_inv(ni * 16 + lrow) * DH_ + lgrp * 8;
    vfp[ni] = Vb + (size_t)(ni * 16 + lrow) * T_ + lgrp * 8;
  }

  const float SC = 0.125f * 1.44269504f;  // scale * log2(e)
  int kvbase = ((lgrp & 1) << 3) | ((lgrp >> 1) << 5);
  const int koff[4] = {0, 4, 16, 20};

  bf16x8 qf[2];
#pragma unroll
  for (int ks = 0; ks < 2; ++ks)
    qf[ks] = *reinterpret_cast<const bf16x8*>(
        Qb + (size_t)(wq0 + lrow) * DH_ + ks * 32 + lgrp * 8);

  f32x4 o[4] = {};
  float l_run = 0.f;

#pragma unroll 1
  for (int kb = 0; kb < nkb; ++kb) {
    // QK^T: K fragments straight from L2 (rows permuted via address)
    f32x4 sreg[4] = {};
#pragma unroll
    for (int ks = 0; ks < 2; ++ks) {
      bf16x8 kf[4];
#pragma unroll
      for (int ni = 0; ni < 4; ++ni)
        kf[ni] = *reinterpret_cast<const bf16x8*>(kfp[ni] + (size_t)kb * 64 * DH_ + ks * 32);
      __builtin_amdgcn_s_setprio(1);
#pragma unroll
      for (int ni = 0; ni < 4; ++ni)
        sreg[ni] = mfma16(kf[ni], qf[ks], sreg[ni]);
      __builtin_amdgcn_s_setprio(0);
    }

    if (kb == qb) {
      int q = wq0 + lrow;
#pragma unroll
      for (int ni = 0; ni < 4; ++ni) {
        int kvb = kb * 64 + kvbase + koff[ni];
#pragma unroll
        for (int r = 0; r < 4; ++r)
          if (kvb + r > q) sreg[ni][r] = -1e30f;
      }
    }

    f32x4 e[4];
#pragma unroll
    for (int ni = 0; ni < 4; ++ni)
#pragma unroll
      for (int r = 0; r < 4; ++r)
        e[ni][r] = __builtin_amdgcn_exp2f(sreg[ni][r] * SC);

    f32x4 ts = (e[0] + e[1]) + (e[2] + e[3]);
    l_run += (ts[0] + ts[1]) + (ts[2] + ts[3]);

    unsigned int Aw[4], Bw[4];
    Aw[0] = cvtpk_bf16(e[0][0], e[0][1]); Aw[1] = cvtpk_bf16(e[0][2], e[0][3]);
    Aw[2] = cvtpk_bf16(e[1][0], e[1][1]); Aw[3] = cvtpk_bf16(e[1][2], e[1][3]);
    Bw[0] = cvtpk_bf16(e[2][0], e[2][1]); Bw[1] = cvtpk_bf16(e[2][2], e[2][3]);
    Bw[2] = cvtpk_bf16(e[3][0], e[3][1]); Bw[3] = cvtpk_bf16(e[3][2], e[3][3]);
    u32x4 p0v, p1v;
#pragma unroll
    for (int ww = 0; ww < 4; ++ww) {
      auto sw = __builtin_amdgcn_permlane32_swap(Aw[ww], Bw[ww], false, false);
      p0v[ww] = sw[0];
      p1v[ww] = sw[1];
    }
    bf16x8 pa[2];
    pa[0] = __builtin_bit_cast(bf16x8, p0v);
    pa[1] = __builtin_bit_cast(bf16x8, p1v);

    // PV: V^T fragments straight from L2
#pragma unroll
    for (int ks = 0; ks < 2; ++ks) {
      bf16x8 vf[4];
#pragma unroll
      for (int di = 0; di < 4; ++di)
        vf[di] = *reinterpret_cast<const bf16x8*>(vfp[di] + (size_t)kb * 64 + ks * 32);
      __builtin_amdgcn_s_setprio(1);
#pragma unroll
      for (int di = 0; di < 4; ++di)
        o[di] = mfma16(pa[ks], vf[di], o[di]);
      __builtin_amdgcn_s_setprio(0);
    }
  }

  float rs = l_run;
  rs += __shfl_xor(rs, 16);
  rs += __shfl_xor(rs, 32);
  float linv = 1.0f / rs;

  int b = bh >> 4, h = bh & 15;
  float lr[4];
#pragma unroll
  for (int r = 0; r < 4; ++r) lr[r] = __shfl(linv, lgrp * 4 + r);
#pragma unroll
  for (int r = 0; r < 4; ++r) {
    int q = wq0 + lgrp * 4 + r;
    size_t base = ((size_t)(b * T_ + q)) * C_ + h * 64 + lrow;
#pragma unroll
    for (int di = 0; di < 4; ++di)
      attno[base + (size_t)di * 16] = f2bf(o[di][r] * lr[r]);
  }
}

extern "C" void kernel_launch(void* const* d_in, const int* in_sizes, int n_in,
                              void* d_out, int out_size, void* d_ws, size_t ws_size,
                              hipStream_t stream) {
  const float* x      = (const float*)d_in[0];
  const float* w_qkv  = (const float*)d_in[1];
  const float* b_qkv  = (const float*)d_in[2];
  const float* w_proj = (const float*)d_in[3];
  const float* b_proj = (const float*)d_in[4];

  char* ws = (char*)d_ws;
  unsigned short* xb     = (unsigned short*)(ws + 0);
  unsigned short* wqkvT  = (unsigned short*)(ws + 8388608);
  unsigned short* wprojT = (unsigned short*)(ws + 14680064);
  unsigned short* qbuf   = (unsigned short*)(ws + 16777216);
  unsigned short* kbuf   = (unsigned short*)(ws + 25165824);
  unsigned short* vtbuf  = (unsigned short*)(ws + 33554432);
  unsigned short* attno  = (unsigned short*)(ws + 41943040);

  prep_kernel<<<8192, 256, 0, stream>>>(x, w_qkv, w_proj, xb, wqkvT, wprojT);
  gemm192_qkv<<<dim3(512), 256, 0, stream>>>(xb, wqkvT, b_qkv, qbuf, kbuf, vtbuf);
  attn_kernel<<<dim3(1024), 256, 0, stream>>>(qbuf, kbuf, vtbuf, attno);
  gemm_proj<<<dim3(256), 256, 0, stream>>>(attno, wprojT, b_proj, (float*)d_out);
}

// Round 22
// 91.117 us; speedup vs baseline: 1.9801x; 1.9801x over previous
//
#include <hip/hip_runtime.h>
#include <hip/hip_bf16.h>

#define B_ 2
#define T_ 2048
#define C_ 1024
#define H_ 16
#define DH_ 64

typedef __attribute__((ext_vector_type(8))) short bf16x8;
typedef __attribute__((ext_vector_type(4))) float f32x4;
typedef __attribute__((ext_vector_type(4))) unsigned int u32x4;

#define DEVI static __device__ __forceinline__

DEVI unsigned short f2bf(float f) {
  unsigned int u = __float_as_uint(f);
  u = (u + 0x7fffu + ((u >> 16) & 1u)) >> 16;
  return (unsigned short)u;
}

DEVI f32x4 mfma16(bf16x8 a, bf16x8 b, f32x4 c) {
  return __builtin_amdgcn_mfma_f32_16x16x32_bf16(a, b, c, 0, 0, 0);
}

DEVI void gload_lds16(const unsigned short* g, unsigned short* l) {
  __builtin_amdgcn_global_load_lds(
      (const __attribute__((address_space(1))) unsigned int*)g,
      (__attribute__((address_space(3))) unsigned int*)l, 16, 0, 0);
}

DEVI unsigned int cvtpk_bf16(float lo, float hi) {
  unsigned int r;
  asm("v_cvt_pk_bf16_f32 %0, %1, %2" : "=v"(r) : "v"(lo), "v"(hi));
  return r;
}

// K-row permutation for attn (R3-verified)
DEVI int kperm(int kv) {
  return (kv & 3) | (((kv >> 3) & 1) << 2) | (((kv >> 5) & 1) << 3) |
         (((kv >> 2) & 1) << 4) | (((kv >> 4) & 1) << 5);
}

// ---- fused pre-pass: x cast + w_qkv transpose-cast + w_proj transpose-cast ----
__global__ __launch_bounds__(256) void prep_kernel(
    const float* __restrict__ x, const float* __restrict__ w_qkv,
    const float* __restrict__ w_proj, unsigned short* __restrict__ xb,
    unsigned short* __restrict__ wqkvT, unsigned short* __restrict__ wprojT) {
  __shared__ float tile[32][33];
  int b = blockIdx.x, tid = threadIdx.x;
  if (b < 4096) {
    int i = b * 256 + tid;
    float4 v = reinterpret_cast<const float4*>(x)[i];
    ushort4 o;
    o.x = f2bf(v.x); o.y = f2bf(v.y); o.z = f2bf(v.z); o.w = f2bf(v.w);
    reinterpret_cast<ushort4*>(xb)[i] = o;
  } else {
    const float* in;
    unsigned short* out;
    int R, C, bb;
    if (b < 7168) { bb = b - 4096; in = w_qkv; out = wqkvT; R = 1024; C = 3072; }
    else          { bb = b - 7168; in = w_proj; out = wprojT; R = 1024; C = 1024; }
    int nbx = C >> 5;
    int c0 = (bb % nbx) * 32, r0 = (bb / nbx) * 32;
    int tx = tid & 31, ty = tid >> 5;
#pragma unroll
    for (int j = 0; j < 32; j += 8)
      tile[ty + j][tx] = in[(size_t)(r0 + ty + j) * C + c0 + tx];
    __syncthreads();
#pragma unroll
    for (int j = 0; j < 32; j += 8)
      out[(size_t)(c0 + ty + j) * R + r0 + tx] = f2bf(tile[tx][ty + j]);
  }
}

// ---- QKV GEMM: 128x192 tile, BK=64, 4 waves, 8-phase, 2 blocks/CU (R18) ----
__global__ __launch_bounds__(256, 2) void gemm192_qkv(
    const unsigned short* __restrict__ A, const unsigned short* __restrict__ Bt,
    const float* __restrict__ bias,
    unsigned short* __restrict__ qbuf, unsigned short* __restrict__ kbuf,
    unsigned short* __restrict__ vtbuf) {
  __shared__ __attribute__((aligned(16))) unsigned short As[2][128 * 64];
  __shared__ __attribute__((aligned(16))) unsigned short Bs[2][192 * 64];
  const int Kd = 1024;
  int tid = threadIdx.x;
  int lane = tid & 63, w = tid >> 6;
  int wn = w;
  int lrow = lane & 15, lgrp = lane >> 4;

  int g = blockIdx.x;
  int gs = (g & 7) * 64 + (g >> 3);
  int by = gs >> 4, bx = gs & 15;
  int bm = by * 128, bn = bx * 192;
  const unsigned short* Ab = A + (size_t)bm * Kd;
  const unsigned short* Bb = Bt + (size_t)bn * Kd;

  int sL[2], scl[2];
#pragma unroll
  for (int it = 0; it < 2; ++it) {
    int c = tid + it * 256;
    int L = c >> 3, s = c & 7, v = s ^ (L & 7);
    sL[it] = L;
    scl[it] = (v >> 2) * 32 + (v & 3) * 8;
  }

  auto stgA = [&](int t, int h) {
    unsigned short* dst = As[t & 1] + h * 4096;
    int k0 = t << 6;
#pragma unroll
    for (int it = 0; it < 2; ++it)
      gload_lds16(Ab + (size_t)(h * 64 + sL[it]) * Kd + k0 + scl[it],
                  dst + (tid + it * 256) * 8);
  };
  auto stgB3 = [&](int t, int th) {
    unsigned short* dst = Bs[t & 1] + th * 4096;
    int k0 = t << 6;
#pragma unroll
    for (int it = 0; it < 2; ++it)
      gload_lds16(Bb + (size_t)(th * 64 + sL[it]) * Kd + k0 + scl[it],
                  dst + (tid + it * 256) * 8);
  };

  auto lda = [&](const unsigned short* buf, int mi, int kk) -> bf16x8 {
    int row = mi * 16 + lrow;
    int s = ((kk << 2) | lgrp) ^ (row & 7);
    return *reinterpret_cast<const bf16x8*>((const char*)buf + row * 128 + s * 16);
  };
  auto ldb = [&](const unsigned short* buf, int ni, int kk) -> bf16x8 {
    int row = wn * 48 + ni * 16 + lrow;
    int s = ((kk << 2) | lgrp) ^ (row & 7);
    return *reinterpret_cast<const bf16x8*>((const char*)buf + row * 128 + s * 16);
  };

  f32x4 acc[8][3] = {};
  bf16x8 bfr[3][2], af[2][2];

#define PHASE_TAIL                                          \
  __builtin_amdgcn_s_barrier();                             \
  __builtin_amdgcn_s_setprio(1);

#define MFMA_TRI(base)                                      \
  _Pragma("unroll") for (int ii = 0; ii < 2; ++ii)          \
  _Pragma("unroll") for (int ni = 0; ni < 3; ++ni) {        \
    acc[(base) + ii][ni] = mfma16(af[ii][0], bfr[ni][0], acc[(base) + ii][ni]); \
    acc[(base) + ii][ni] = mfma16(af[ii][1], bfr[ni][1], acc[(base) + ii][ni]); \
  }

#define PHASE_END                                           \
  __builtin_amdgcn_s_setprio(0);                            \
  __builtin_amdgcn_s_barrier();

  stgA(0, 0); stgA(0, 1);
  stgB3(0, 0); stgB3(0, 1); stgB3(0, 2);
  stgB3(1, 0); stgB3(1, 1); stgB3(1, 2);
  asm volatile("s_waitcnt vmcnt(6)" ::: "memory");
  __builtin_amdgcn_s_barrier();

#pragma unroll 1
  for (int j = 0; j < 8; ++j) {
    const bool nl = (j < 7);
    const int t1 = 2 * j + 1, t2 = 2 * j + 2, t3 = 2 * j + 3;

#pragma unroll
    for (int ni = 0; ni < 3; ++ni) { bfr[ni][0] = ldb(Bs[0], ni, 0); bfr[ni][1] = ldb(Bs[0], ni, 1); }
    af[0][0] = lda(As[0], 0, 0); af[0][1] = lda(As[0], 0, 1);
    af[1][0] = lda(As[0], 1, 0); af[1][1] = lda(As[0], 1, 1);
    stgA(t1, 0);
    PHASE_TAIL; MFMA_TRI(0); PHASE_END;

    af[0][0] = lda(As[0], 2, 0); af[0][1] = lda(As[0], 2, 1);
    af[1][0] = lda(As[0], 3, 0); af[1][1] = lda(As[0], 3, 1);
    stgA(t1, 1);
    if (nl) stgB3(t2, 0);
    PHASE_TAIL; MFMA_TRI(2); PHASE_END;

    af[0][0] = lda(As[0], 4, 0); af[0][1] = lda(As[0], 4, 1);
    af[1][0] = lda(As[0], 5, 0); af[1][1] = lda(As[0], 5, 1);
    if (nl) stgB3(t2, 1);
    PHASE_TAIL; MFMA_TRI(4); PHASE_END;

    af[0][0] = lda(As[0], 6, 0); af[0][1] = lda(As[0], 6, 1);
    af[1][0] = lda(As[0], 7, 0); af[1][1] = lda(As[0], 7, 1);
    if (nl) stgB3(t2, 2);
    PHASE_TAIL; MFMA_TRI(6);
    __builtin_amdgcn_s_setprio(0);
    if (nl) { asm volatile("s_waitcnt vmcnt(6)" ::: "memory"); }
    else    { asm volatile("s_waitcnt vmcnt(0)" ::: "memory"); }
    __builtin_amdgcn_s_barrier();

#pragma unroll
    for (int ni = 0; ni < 3; ++ni) { bfr[ni][0] = ldb(Bs[1], ni, 0); bfr[ni][1] = ldb(Bs[1], ni, 1); }
    af[0][0] = lda(As[1], 0, 0); af[0][1] = lda(As[1], 0, 1);
    af[1][0] = lda(As[1], 1, 0); af[1][1] = lda(As[1], 1, 1);
    if (nl) stgA(t2, 0);
    PHASE_TAIL; MFMA_TRI(0); PHASE_END;

    af[0][0] = lda(As[1], 2, 0); af[0][1] = lda(As[1], 2, 1);
    af[1][0] = lda(As[1], 3, 0); af[1][1] = lda(As[1], 3, 1);
    if (nl) { stgA(t2, 1); stgB3(t3, 0); }
    PHASE_TAIL; MFMA_TRI(2); PHASE_END;

    af[0][0] = lda(As[1], 4, 0); af[0][1] = lda(As[1], 4, 1);
    af[1][0] = lda(As[1], 5, 0); af[1][1] = lda(As[1], 5, 1);
    if (nl) stgB3(t3, 1);
    PHASE_TAIL; MFMA_TRI(4); PHASE_END;

    af[0][0] = lda(As[1], 6, 0); af[0][1] = lda(As[1], 6, 1);
    af[1][0] = lda(As[1], 7, 0); af[1][1] = lda(As[1], 7, 1);
    if (nl) stgB3(t3, 2);
    PHASE_TAIL; MFMA_TRI(6);
    __builtin_amdgcn_s_setprio(0);
    if (nl) { asm volatile("s_waitcnt vmcnt(6)" ::: "memory"); }
    __builtin_amdgcn_s_barrier();
  }
#undef PHASE_TAIL
#undef MFMA_TRI
#undef PHASE_END

  int c0 = bn + wn * 48;
#pragma unroll
  for (int ni = 0; ni < 3; ++ni) {
    int col = c0 + ni * 16 + lrow;
    float bv = bias[col];
    int which = col >> 10, cc = col & 1023;
    int h = cc >> 6, d = cc & 63;
#pragma unroll
    for (int mi = 0; mi < 8; ++mi) {
      int rowb = bm + mi * 16 + lgrp * 4;
      int b = rowb >> 11, tt = rowb & 2047;
      if (which == 2) {
        ushort4 pk;
        pk.x = f2bf(acc[mi][ni][0] + bv);
        pk.y = f2bf(acc[mi][ni][1] + bv);
        pk.z = f2bf(acc[mi][ni][2] + bv);
        pk.w = f2bf(acc[mi][ni][3] + bv);
        *reinterpret_cast<ushort4*>(vtbuf + ((size_t)((b * 16 + h) * 64 + d)) * T_ + tt) = pk;
      } else {
        unsigned short* dst = (which == 0) ? qbuf : kbuf;
        size_t base = ((size_t)(b * 16 + h) * T_ + tt) * DH_ + d;
#pragma unroll
        for (int r = 0; r < 4; ++r)
          dst[base + (size_t)r * DH_] = f2bf(acc[mi][ni][r] + bv);
      }
    }
  }
}

// ---- proj GEMM: 128x128 tile, BK=64, 4 waves, 8-phase, 2 blocks/CU (R18) ----
__global__ __launch_bounds__(256, 2) void gemm_proj(
    const unsigned short* __restrict__ A, const unsigned short* __restrict__ Bt,
    const float* __restrict__ bias, float* __restrict__ outp) {
  __shared__ __attribute__((aligned(16))) unsigned short As[2][128 * 64];
  __shared__ __attribute__((aligned(16))) unsigned short Bs[2][128 * 64];
  const int Kd = 1024, Nd = 1024;
  int tid = threadIdx.x;
  int lane = tid & 63, w = tid >> 6;
  int wn = w;
  int lrow = lane & 15, lgrp = lane >> 4;

  int g = blockIdx.x;
  int gs = (g & 7) * 32 + (g >> 3);
  int by = gs >> 3, bx = gs & 7;
  int bm = by * 128, bn = bx * 128;
  const unsigned short* Ab = A + (size_t)bm * Kd;
  const unsigned short* Bb = Bt + (size_t)bn * Kd;

  int sL[2], scl[2];
#pragma unroll
  for (int it = 0; it < 2; ++it) {
    int c = tid + it * 256;
    int L = c >> 3, s = c & 7, v = s ^ (L & 7);
    sL[it] = L;
    scl[it] = (v >> 2) * 32 + (v & 3) * 8;
  }

  auto stgA = [&](int t, int h) {
    unsigned short* dst = As[t & 1] + h * 4096;
    int k0 = t << 6;
#pragma unroll
    for (int it = 0; it < 2; ++it)
      gload_lds16(Ab + (size_t)(h * 64 + sL[it]) * Kd + k0 + scl[it],
                  dst + (tid + it * 256) * 8);
  };
  auto stgB = [&](int t, int h) {
    unsigned short* dst = Bs[t & 1] + h * 4096;
    int k0 = t << 6;
#pragma unroll
    for (int it = 0; it < 2; ++it)
      gload_lds16(Bb + (size_t)(h * 64 + sL[it]) * Kd + k0 + scl[it],
                  dst + (tid + it * 256) * 8);
  };

  auto lda = [&](const unsigned short* buf, int mi, int kk) -> bf16x8 {
    int row = mi * 16 + lrow;
    int s = ((kk << 2) | lgrp) ^ (row & 7);
    return *reinterpret_cast<const bf16x8*>((const char*)buf + row * 128 + s * 16);
  };
  auto ldb = [&](const unsigned short* buf, int ni, int kk) -> bf16x8 {
    int row = wn * 32 + ni * 16 + lrow;
    int s = ((kk << 2) | lgrp) ^ (row & 7);
    return *reinterpret_cast<const bf16x8*>((const char*)buf + row * 128 + s * 16);
  };

  f32x4 acc[8][2] = {};
  bf16x8 bfr[2][2], af[2][2];

#define PHASE_TAIL                                          \
  __builtin_amdgcn_s_barrier();                             \
  __builtin_amdgcn_s_setprio(1);

#define MFMA_DUO(base)                                      \
  _Pragma("unroll") for (int ii = 0; ii < 2; ++ii)          \
  _Pragma("unroll") for (int ni = 0; ni < 2; ++ni) {        \
    acc[(base) + ii][ni] = mfma16(af[ii][0], bfr[ni][0], acc[(base) + ii][ni]); \
    acc[(base) + ii][ni] = mfma16(af[ii][1], bfr[ni][1], acc[(base) + ii][ni]); \
  }

#define PHASE_END                                           \
  __builtin_amdgcn_s_setprio(0);                            \
  __builtin_amdgcn_s_barrier();

  stgA(0, 0); stgA(0, 1); stgB(0, 0); stgB(0, 1);
  stgB(1, 0); stgB(1, 1);
  asm volatile("s_waitcnt vmcnt(4)" ::: "memory");
  __builtin_amdgcn_s_barrier();

#pragma unroll 1
  for (int j = 0; j < 8; ++j) {
    const bool nl = (j < 7);
    const int t1 = 2 * j + 1, t2 = 2 * j + 2, t3 = 2 * j + 3;

#pragma unroll
    for (int ni = 0; ni < 2; ++ni) { bfr[ni][0] = ldb(Bs[0], ni, 0); bfr[ni][1] = ldb(Bs[0], ni, 1); }
    af[0][0] = lda(As[0], 0, 0); af[0][1] = lda(As[0], 0, 1);
    af[1][0] = lda(As[0], 1, 0); af[1][1] = lda(As[0], 1, 1);
    stgA(t1, 0);
    PHASE_TAIL; MFMA_DUO(0); PHASE_END;

    af[0][0] = lda(As[0], 2, 0); af[0][1] = lda(As[0], 2, 1);
    af[1][0] = lda(As[0], 3, 0); af[1][1] = lda(As[0], 3, 1);
    stgA(t1, 1);
    if (nl) stgB(t2, 0);
    PHASE_TAIL; MFMA_DUO(2); PHASE_END;

    af[0][0] = lda(As[0], 4, 0); af[0][1] = lda(As[0], 4, 1);
    af[1][0] = lda(As[0], 5, 0); af[1][1] = lda(As[0], 5, 1);
    if (nl) stgB(t2, 1);
    PHASE_TAIL; MFMA_DUO(4); PHASE_END;

    af[0][0] = lda(As[0], 6, 0); af[0][1] = lda(As[0], 6, 1);
    af[1][0] = lda(As[0], 7, 0); af[1][1] = lda(As[0], 7, 1);
    PHASE_TAIL; MFMA_DUO(6);
    __builtin_amdgcn_s_setprio(0);
    if (nl) { asm volatile("s_waitcnt vmcnt(4)" ::: "memory"); }
    else    { asm volatile("s_waitcnt vmcnt(0)" ::: "memory"); }
    __builtin_amdgcn_s_barrier();

#pragma unroll
    for (int ni = 0; ni < 2; ++ni) { bfr[ni][0] = ldb(Bs[1], ni, 0); bfr[ni][1] = ldb(Bs[1], ni, 1); }
    af[0][0] = lda(As[1], 0, 0); af[0][1] = lda(As[1], 0, 1);
    af[1][0] = lda(As[1], 1, 0); af[1][1] = lda(As[1], 1, 1);
    if (nl) stgA(t2, 0);
    PHASE_TAIL; MFMA_DUO(0); PHASE_END;

    af[0][0] = lda(As[1], 2, 0); af[0][1] = lda(As[1], 2, 1);
    af[1][0] = lda(As[1], 3, 0); af[1][1] = lda(As[1], 3, 1);
    if (nl) { stgA(t2, 1); stgB(t3, 0); }
    PHASE_TAIL; MFMA_DUO(2); PHASE_END;

    af[0][0] = lda(As[1], 4, 0); af[0][1] = lda(As[1], 4, 1);
    af[1][0] = lda(As[1], 5, 0); af[1][1] = lda(As[1], 5, 1);
    if (nl) stgB(t3, 1);
    PHASE_TAIL; MFMA_DUO(4); PHASE_END;

    af[0][0] = lda(As[1], 6, 0); af[0][1] = lda(As[1], 6, 1);
    af[1][0] = lda(As[1], 7, 0); af[1][1] = lda(As[1], 7, 1);
    PHASE_TAIL; MFMA_DUO(6);
    __builtin_amdgcn_s_setprio(0);
    if (nl) { asm volatile("s_waitcnt vmcnt(4)" ::: "memory"); }
    __builtin_amdgcn_s_barrier();
  }
#undef PHASE_TAIL
#undef MFMA_DUO
#undef PHASE_END

  int c0 = bn + wn * 32;
#pragma unroll
  for (int ni = 0; ni < 2; ++ni) {
    int col = c0 + ni * 16 + lrow;
    float bv = bias[col];
#pragma unroll
    for (int mi = 0; mi < 8; ++mi) {
      int rowb = bm + mi * 16 + lgrp * 4;
#pragma unroll
      for (int r = 0; r < 4; ++r)
        outp[(size_t)(rowb + r) * Nd + col] = acc[mi][ni][r] + bv;
    }
  }
}

// ---- flash attention: NO-MAX softmax, QBLK=128 (8 waves x 16 rows), R20 best ----
__global__ __launch_bounds__(512, 2) void attn_kernel(
    const unsigned short* __restrict__ qbuf,
    const unsigned short* __restrict__ kbuf,
    const unsigned short* __restrict__ vtbuf,
    unsigned short* __restrict__ attno) {
  __shared__ __attribute__((aligned(16))) unsigned short Ks[64 * 64];
  __shared__ __attribute__((aligned(16))) unsigned short Vts[64 * 64];

  int tid = threadIdx.x;
  int lane = tid & 63, w = tid >> 6;      // 8 waves
  int lrow = lane & 15, lgrp = lane >> 4;

  int g = blockIdx.x;                     // 512 blocks
  int s = g >> 8;                         // CU-mate slot (0,1)
  int idx = g & 255;
  int bh = idx & 31;                      // head in low bits (XCD L2 locality)
  int pp = idx >> 5;                      // 0..7
  int p = s ? (15 - pp) : pp;             // q-tile (128 rows); mates sum to 34 iters
  int wq0 = p * 128 + w * 16;
  int nkb = 2 * p + 2;

  const unsigned short* Qb = qbuf + (size_t)bh * T_ * DH_;
  const unsigned short* Kb = kbuf + (size_t)bh * T_ * DH_;
  const unsigned short* Vb = vtbuf + (size_t)bh * DH_ * T_;

  // staging: 512 threads x (1 K-chunk + 1 V-chunk of 16B)
  int srow = tid >> 3, scol = tid & 7;    // srow 0..63
  int pkr = kperm(srow);
  int soffK = pkr * 128 + ((scol * 16) ^ ((pkr & 7) << 4));
  int soffV = srow * 128 + ((scol * 16) ^ ((srow & 7) << 4));

  const float SC = 0.125f * 1.44269504f;  // scale * log2(e)
  int kvbase = ((lgrp & 1) << 3) | ((lgrp >> 1) << 5);
  const int koff[4] = {0, 4, 16, 20};

  bf16x8 qf[2];
#pragma unroll
  for (int ks = 0; ks < 2; ++ks)
    qf[ks] = *reinterpret_cast<const bf16x8*>(
        Qb + (size_t)(wq0 + lrow) * DH_ + ks * 32 + lgrp * 8);

  f32x4 o[4] = {};
  float l_run = 0.f;

  bf16x8 sk, sv;
  auto stage_load = [&](int kb) {
    sk = *reinterpret_cast<const bf16x8*>(Kb + (size_t)(kb * 64 + srow) * DH_ + scol * 8);
    sv = *reinterpret_cast<const bf16x8*>(Vb + (size_t)srow * T_ + kb * 64 + scol * 8);
  };
  auto stage_write = [&]() {
    *reinterpret_cast<bf16x8*>((char*)Ks + soffK) = sk;
    *reinterpret_cast<bf16x8*>((char*)Vts + soffV) = sv;
  };

  stage_load(0);
#pragma unroll 1
  for (int kb = 0; kb < nkb; ++kb) {
    if (kb > 0) __syncthreads();
    stage_write();
    __syncthreads();
    if (kb + 1 < nkb) stage_load(kb + 1);

    f32x4 sreg[4] = {};
#pragma unroll
    for (int ks = 0; ks < 2; ++ks) {
      bf16x8 kf[4];
#pragma unroll
      for (int ni = 0; ni < 4; ++ni) {
        int kr = ni * 16 + lrow;
        int off = kr * 128 + (((ks * 32 + lgrp * 8) * 2) ^ ((kr & 7) << 4));
        kf[ni] = *reinterpret_cast<const bf16x8*>((const char*)Ks + off);
      }
      __builtin_amdgcn_s_setprio(1);
#pragma unroll
      for (int ni = 0; ni < 4; ++ni)
        sreg[ni] = mfma16(kf[ni], qf[ks], sreg[ni]);
      __builtin_amdgcn_s_setprio(0);
    }

    if (kb * 64 + 63 > wq0) {  // diagonal/above region for this wave
      int q = wq0 + lrow;
#pragma unroll
      for (int ni = 0; ni < 4; ++ni) {
        int kvb = kb * 64 + kvbase + koff[ni];
#pragma unroll
        for (int r = 0; r < 4; ++r)
          if (kvb + r > q) sreg[ni][r] = -1e30f;
      }
    }

    f32x4 e[4];
#pragma unroll
    for (int ni = 0; ni < 4; ++ni)
#pragma unroll
      for (int r = 0; r < 4; ++r)
        e[ni][r] = __builtin_amdgcn_exp2f(sreg[ni][r] * SC);

    f32x4 ts = (e[0] + e[1]) + (e[2] + e[3]);
    l_run += (ts[0] + ts[1]) + (ts[2] + ts[3]);

    unsigned int Aw[4], Bw[4];
    Aw[0] = cvtpk_bf16(e[0][0], e[0][1]); Aw[1] = cvtpk_bf16(e[0][2], e[0][3]);
    Aw[2] = cvtpk_bf16(e[1][0], e[1][1]); Aw[3] = cvtpk_bf16(e[1][2], e[1][3]);
    Bw[0] = cvtpk_bf16(e[2][0], e[2][1]); Bw[1] = cvtpk_bf16(e[2][2], e[2][3]);
    Bw[2] = cvtpk_bf16(e[3][0], e[3][1]); Bw[3] = cvtpk_bf16(e[3][2], e[3][3]);
    u32x4 p0v, p1v;
#pragma unroll
    for (int ww = 0; ww < 4; ++ww) {
      auto sw = __builtin_amdgcn_permlane32_swap(Aw[ww], Bw[ww], false, false);
      p0v[ww] = sw[0];
      p1v[ww] = sw[1];
    }
    bf16x8 pa[2];
    pa[0] = __builtin_bit_cast(bf16x8, p0v);
    pa[1] = __builtin_bit_cast(bf16x8, p1v);

#pragma unroll
    for (int ks = 0; ks < 2; ++ks) {
      bf16x8 vf[4];
#pragma unroll
      for (int di = 0; di < 4; ++di) {
        int vr = di * 16 + lrow;
        int off = vr * 128 + (((ks * 32 + lgrp * 8) * 2) ^ ((vr & 7) << 4));
        vf[di] = *reinterpret_cast<const bf16x8*>((const char*)Vts + off);
      }
      __builtin_amdgcn_s_setprio(1);
#pragma unroll
      for (int di = 0; di < 4; ++di)
        o[di] = mfma16(pa[ks], vf[di], o[di]);
      __builtin_amdgcn_s_setprio(0);
    }
  }

  float rs = l_run;
  rs += __shfl_xor(rs, 16);
  rs += __shfl_xor(rs, 32);
  float linv = 1.0f / rs;

  int b = bh >> 4, h = bh & 15;
  float lr[4];
#pragma unroll
  for (int r = 0; r < 4; ++r) lr[r] = __shfl(linv, lgrp * 4 + r);
#pragma unroll
  for (int r = 0; r < 4; ++r) {
    int q = wq0 + lgrp * 4 + r;
    size_t base = ((size_t)(b * T_ + q)) * C_ + h * 64 + lrow;
#pragma unroll
    for (int di = 0; di < 4; ++di)
      attno[base + (size_t)di * 16] = f2bf(o[di][r] * lr[r]);
  }
}

extern "C" void kernel_launch(void* const* d_in, const int* in_sizes, int n_in,
                              void* d_out, int out_size, void* d_ws, size_t ws_size,
                              hipStream_t stream) {
  const float* x      = (const float*)d_in[0];
  const float* w_qkv  = (const float*)d_in[1];
  const float* b_qkv  = (const float*)d_in[2];
  const float* w_proj = (const float*)d_in[3];
  const float* b_proj = (const float*)d_in[4];

  char* ws = (char*)d_ws;
  unsigned short* xb     = (unsigned short*)(ws + 0);
  unsigned short* wqkvT  = (unsigned short*)(ws + 8388608);
  unsigned short* wprojT = (unsigned short*)(ws + 14680064);
  unsigned short* qbuf   = (unsigned short*)(ws + 16777216);
  unsigned short* kbuf   = (unsigned short*)(ws + 25165824);
  unsigned short* vtbuf  = (unsigned short*)(ws + 33554432);
  unsigned short* attno  = (unsigned short*)(ws + 41943040);

  prep_kernel<<<8192, 256, 0, stream>>>(x, w_qkv, w_proj, xb, wqkvT, wprojT);
  gemm192_qkv<<<dim3(512), 256, 0, stream>>>(xb, wqkvT, b_qkv, qbuf, kbuf, vtbuf);
  attn_kernel<<<dim3(512), 512, 0, stream>>>(qbuf, kbuf, vtbuf, attno);
  gemm_proj<<<dim3(256), 256, 0, stream>>>(attno, wprojT, b_proj, (float*)d_out);
}